// Round 4
// baseline (1592.897 us; speedup 1.0000x reference)
//
#include <hip/hip_runtime.h>

#define N_BINS 15
#define BLOCKS 1024

typedef float f4 __attribute__((ext_vector_type(4)));

__device__ __forceinline__ float max4(f4 v) {
    return fmaxf(fmaxf(v[0], v[1]), fmaxf(v[2], v[3]));
}

// ABLATION BUILD: r1-best fused kernel + TWO extra full-coverage read streams
// (rows rotated by n/3 and 2n/3). Extra data is consumed only by an empty
// inline-asm (kept live, rule #17) — output math identical, FETCH_SIZE x3.
// Purpose: measure ece_main's true BW by making it big enough to show in
// the top-5 dispatch table (or prove it can't).
__global__ __launch_bounds__(256) void ece_main(
    const float* __restrict__ probs,
    const int* __restrict__ labels,
    const int* __restrict__ is_logit_p,
    float* __restrict__ bins,
    int n_rows)
{
    __shared__ float s_bins[4][3][17];

    const int tid = threadIdx.x;
    if (tid < 4 * 3 * 17) ((float*)s_bins)[tid] = 0.f;
    __syncthreads();

    const int is_logit = *is_logit_p;   // wave-uniform
    const int lane = tid & 63;
    const int wave = tid >> 6;
    const int sub  = tid & 7;           // lane within 8-lane row group
    const int grp  = tid >> 3;          // row group within block: 0..31

    long long row = (long long)blockIdx.x * 32 + grp;
    const long long stride = (long long)gridDim.x * 32;
    const long long third  = n_rows / 3;

    for (; row < n_rows; row += stride) {
        const f4* rp = (const f4*)probs + (size_t)row * 32 + sub;
        const f4 v0 = rp[0], v1 = rp[8], v2 = rp[16], v3 = rp[24];
        const int lab = labels[row];

        // ---- extra streams (ablation): rows row+n/3, row+2n/3 (wrapped) ----
        long long rb = row + third;      if (rb >= n_rows) rb -= n_rows;
        long long rc = row + 2 * third;  if (rc >= n_rows) rc -= n_rows;
        {
            const f4* bp = (const f4*)probs + (size_t)rb * 32 + sub;
            const f4* cp = (const f4*)probs + (size_t)rc * 32 + sub;
            const f4 b0 = bp[0], b1 = bp[8], b2 = bp[16], b3 = bp[24];
            const f4 c0 = cp[0], c1 = cp[8], c2 = cp[16], c3 = cp[24];
            float d = fmaxf(fmaxf(max4(b0), max4(b1)), fmaxf(max4(b2), max4(b3)));
            d = fmaxf(d, fmaxf(fmaxf(max4(c0), max4(c1)), fmaxf(max4(c2), max4(c3))));
            asm volatile("" :: "v"(d));   // keep live, no output effect
        }

        // ---- actual ECE math (identical to r1) ----
        float m = fmaxf(fmaxf(max4(v0), max4(v1)), fmaxf(max4(v2), max4(v3)));
        m = fmaxf(m, __shfl_xor(m, 1, 64));
        m = fmaxf(m, __shfl_xor(m, 2, 64));
        m = fmaxf(m, __shfl_xor(m, 4, 64));

        float conf;
        if (is_logit) {
            float s = (__expf(v0[0]-m)+__expf(v0[1]-m))+(__expf(v0[2]-m)+__expf(v0[3]-m))
                    + (__expf(v1[0]-m)+__expf(v1[1]-m))+(__expf(v1[2]-m)+__expf(v1[3]-m))
                    + (__expf(v2[0]-m)+__expf(v2[1]-m))+(__expf(v2[2]-m)+__expf(v2[3]-m))
                    + (__expf(v3[0]-m)+__expf(v3[1]-m))+(__expf(v3[2]-m)+__expf(v3[3]-m));
            s += __shfl_xor(s, 1, 64);
            s += __shfl_xor(s, 2, 64);
            s += __shfl_xor(s, 4, 64);
            conf = 1.0f / s;
        } else {
            conf = m;
        }

        const int f = lab >> 2, c = lab & 3, k = f >> 3;
        f4 vk = (k == 0) ? v0 : (k == 1) ? v1 : (k == 2) ? v2 : v3;
        float lv = (c == 0) ? vk[0] : (c == 1) ? vk[1] : (c == 2) ? vk[2] : vk[3];
        const bool mine = ((f & 7) == sub) && (lv == m);
        const unsigned long long bal = __ballot(mine);

        if (sub == 0) {
            int bin = (int)ceilf(conf * (float)N_BINS) - 1;
            bin = bin < 0 ? 0 : (bin > N_BINS - 1 ? N_BINS - 1 : bin);
            const float acc = ((bal >> (lane & 56)) & 0xFFull) ? 1.0f : 0.0f;
            atomicAdd(&s_bins[wave][0][bin], 1.0f);
            atomicAdd(&s_bins[wave][1][bin], conf);
            atomicAdd(&s_bins[wave][2][bin], acc);
        }
    }

    __syncthreads();
    if (tid < 3 * N_BINS) {
        const int c = tid / N_BINS;
        const int b = tid - c * N_BINS;
        atomicAdd(&bins[tid], s_bins[0][c][b] + s_bins[1][c][b]
                            + s_bins[2][c][b] + s_bins[3][c][b]);
    }
}

__global__ void ece_final(const float* __restrict__ bins,
                          float* __restrict__ out, int n_rows)
{
    if (threadIdx.x == 0 && blockIdx.x == 0) {
        float ece = 0.f;
        for (int i = 0; i < N_BINS; ++i) {
            float c = bins[i];
            if (c > 0.f) {
                float gap = fabsf(bins[N_BINS + i] / c - bins[2 * N_BINS + i] / c);
                ece += gap * (c / (float)n_rows);
            }
        }
        out[0] = ece;
    }
}

extern "C" void kernel_launch(void* const* d_in, const int* in_sizes, int n_in,
                              void* d_out, int out_size, void* d_ws, size_t ws_size,
                              hipStream_t stream) {
    const float* probs    = (const float*)d_in[0];
    const int*   labels   = (const int*)d_in[1];
    const int*   is_logit = (const int*)d_in[2];
    float*       out      = (float*)d_out;
    float*       bins     = (float*)d_ws;
    const int n_rows = in_sizes[1];   // 2,000,000

    hipMemsetAsync(bins, 0, 3 * N_BINS * sizeof(float), stream);
    ece_main<<<BLOCKS, 256, 0, stream>>>(probs, labels, is_logit, bins, n_rows);
    ece_final<<<1, 64, 0, stream>>>(bins, out, n_rows);
}

// Round 5
// 1263.848 us; speedup vs baseline: 1.2604x; 1.2604x over previous
//
#include <hip/hip_runtime.h>

#define N_BINS 15
#define BLOCKS 1024

typedef float f4 __attribute__((ext_vector_type(4)));

__device__ __forceinline__ float max4(f4 v) {
    return fmaxf(fmaxf(v[0], v[1]), fmaxf(v[2], v[3]));
}

// Roofline note (r4 ablation): this kernel's read path streams at ~5.75 TB/s
// marginal (91% of achievable). Kernel cost ~180 us vs 163 us HBM floor;
// total dur_us is dominated by the harness's 4 GB poison fill (~640 us) +
// reset dispatch train (~415 us). Structure variants are within noise.
// d_ws layout (floats): [0..14]=count, [15..29]=conf_sum, [30..44]=acc_sum
__global__ __launch_bounds__(256) void ece_main(
    const float* __restrict__ probs,
    const int* __restrict__ labels,
    const int* __restrict__ is_logit_p,
    float* __restrict__ bins,
    int n_rows)
{
    // per-wave partial bins: wave -> component(count,conf,acc) -> bin (padded 17)
    __shared__ float s_bins[4][3][17];

    const int tid = threadIdx.x;
    if (tid < 4 * 3 * 17) ((float*)s_bins)[tid] = 0.f;
    __syncthreads();

    const int is_logit = *is_logit_p;   // wave-uniform
    const int lane = tid & 63;
    const int wave = tid >> 6;          // 0..3
    const int sub  = tid & 7;           // lane within 8-lane row group
    const int grp  = tid >> 3;          // row group within block: 0..31

    long long row = (long long)blockIdx.x * 32 + grp;
    const long long stride = (long long)gridDim.x * 32;

    for (; row < n_rows; row += stride) {
        const f4* rp = (const f4*)probs + (size_t)row * 32 + sub;
        const f4 v0 = rp[0], v1 = rp[8], v2 = rp[16], v3 = rp[24];
        const int lab = labels[row];

        // ---- local max over 16 elements (tree) ----
        float m = fmaxf(fmaxf(max4(v0), max4(v1)), fmaxf(max4(v2), max4(v3)));
        // ---- group max: 3 xor-shuffles within the 8-lane group ----
        m = fmaxf(m, __shfl_xor(m, 1, 64));
        m = fmaxf(m, __shfl_xor(m, 2, 64));
        m = fmaxf(m, __shfl_xor(m, 4, 64));

        // ---- confidence ----
        float conf;
        if (is_logit) {
            float s = (__expf(v0[0]-m)+__expf(v0[1]-m))+(__expf(v0[2]-m)+__expf(v0[3]-m))
                    + (__expf(v1[0]-m)+__expf(v1[1]-m))+(__expf(v1[2]-m)+__expf(v1[3]-m))
                    + (__expf(v2[0]-m)+__expf(v2[1]-m))+(__expf(v2[2]-m)+__expf(v2[3]-m))
                    + (__expf(v3[0]-m)+__expf(v3[1]-m))+(__expf(v3[2]-m)+__expf(v3[3]-m));
            s += __shfl_xor(s, 1, 64);
            s += __shfl_xor(s, 2, 64);
            s += __shfl_xor(s, 4, 64);
            conf = 1.0f / s;            // max softmax prob = 1 / sum(exp(x-m))
        } else {
            conf = m;
        }

        // ---- accuracy: does the label position hold the row max? ----
        const int f = lab >> 2;         // float4 index of label
        const int c = lab & 3;          // component
        const int k = f >> 3;           // which of v0..v3
        f4 vk = (k == 0) ? v0 : (k == 1) ? v1 : (k == 2) ? v2 : v3;
        float lv = (c == 0) ? vk[0] : (c == 1) ? vk[1] : (c == 2) ? vk[2] : vk[3];
        const bool mine = ((f & 7) == sub) && (lv == m);
        const unsigned long long bal = __ballot(mine);

        if (sub == 0) {
            int bin = (int)ceilf(conf * (float)N_BINS) - 1;
            bin = bin < 0 ? 0 : (bin > N_BINS - 1 ? N_BINS - 1 : bin);
            const float acc = ((bal >> (lane & 56)) & 0xFFull) ? 1.0f : 0.0f;
            atomicAdd(&s_bins[wave][0][bin], 1.0f);
            atomicAdd(&s_bins[wave][1][bin], conf);
            atomicAdd(&s_bins[wave][2][bin], acc);
        }
    }

    __syncthreads();
    if (tid < 3 * N_BINS) {
        const int c = tid / N_BINS;
        const int b = tid - c * N_BINS;
        atomicAdd(&bins[tid], s_bins[0][c][b] + s_bins[1][c][b]
                            + s_bins[2][c][b] + s_bins[3][c][b]);
    }
}

__global__ void ece_final(const float* __restrict__ bins,
                          float* __restrict__ out, int n_rows)
{
    if (threadIdx.x == 0 && blockIdx.x == 0) {
        float ece = 0.f;
        for (int i = 0; i < N_BINS; ++i) {
            float c = bins[i];
            if (c > 0.f) {
                float gap = fabsf(bins[N_BINS + i] / c - bins[2 * N_BINS + i] / c);
                ece += gap * (c / (float)n_rows);
            }
        }
        out[0] = ece;
    }
}

extern "C" void kernel_launch(void* const* d_in, const int* in_sizes, int n_in,
                              void* d_out, int out_size, void* d_ws, size_t ws_size,
                              hipStream_t stream) {
    const float* probs    = (const float*)d_in[0];
    const int*   labels   = (const int*)d_in[1];
    const int*   is_logit = (const int*)d_in[2];
    float*       out      = (float*)d_out;
    float*       bins     = (float*)d_ws;
    const int n_rows = in_sizes[1];   // 2,000,000

    hipMemsetAsync(bins, 0, 3 * N_BINS * sizeof(float), stream);
    ece_main<<<BLOCKS, 256, 0, stream>>>(probs, labels, is_logit, bins, n_rows);
    ece_final<<<1, 64, 0, stream>>>(bins, out, n_rows);
}